// Round 1
// baseline (1028.409 us; speedup 1.0000x reference)
//
#include <hip/hip_runtime.h>
#include <stdint.h>

#define MM 1024
#define NN 1024
#define DD 64
#define PP 4096
#define HH 16
#define LL 5120   // P + M

typedef float  f32x4  __attribute__((ext_vector_type(4)));
typedef short  s16x8  __attribute__((ext_vector_type(8)));
typedef short  s16x4  __attribute__((ext_vector_type(4)));
typedef __bf16 bf16x8 __attribute__((ext_vector_type(8)));

static __device__ __forceinline__ unsigned short f2bf(float f) {
    unsigned u = __float_as_uint(f);
    u += 0x7FFFu + ((u >> 16) & 1u);   // RNE (no NaNs in this workload)
    return (unsigned short)(u >> 16);
}
static __device__ __forceinline__ float bf2f(unsigned short h) {
    return __uint_as_float(((unsigned)h) << 16);
}
static __device__ __forceinline__ f32x4 mfma16(s16x8 a, s16x8 b, f32x4 c) {
    return __builtin_amdgcn_mfma_f32_16x16x32_bf16(
        __builtin_bit_cast(bf16x8, a), __builtin_bit_cast(bf16x8, b), c, 0, 0, 0);
}

// ---------------- prep: cast X -> (Xh, Xl) bf16 split; cast cache_K into K_all[h][0..P-1][d]
__global__ void k_prep(const float* __restrict__ X, const float* __restrict__ cK,
                       unsigned short* __restrict__ Xh, unsigned short* __restrict__ Xl,
                       unsigned short* __restrict__ Kall) {
    const int nX4 = (MM * NN) / 4;        // 262144
    const int nK4 = (HH * PP * DD) / 4;   // 1048576
    int stride = gridDim.x * blockDim.x;
    for (int i = blockIdx.x * blockDim.x + threadIdx.x; i < nX4 + nK4; i += stride) {
        if (i < nX4) {
            f32x4 v = reinterpret_cast<const f32x4*>(X)[i];
            s16x4 h, l;
            for (int j = 0; j < 4; ++j) {
                float f = v[j];
                unsigned short hb = f2bf(f);
                h[j] = (short)hb;
                l[j] = (short)f2bf(f - bf2f(hb));
            }
            reinterpret_cast<s16x4*>(Xh)[i] = h;
            reinterpret_cast<s16x4*>(Xl)[i] = l;
        } else {
            int j = i - nX4;
            f32x4 v = reinterpret_cast<const f32x4*>(cK)[j];
            s16x4 h;
            for (int jj = 0; jj < 4; ++jj) h[jj] = (short)f2bf(v[jj]);
            int e = j * 4;
            int hh = e >> 18;              // P*D = 262144 = 2^18
            int rem = e & 262143;
            int64_t de = (int64_t)hh * (LL * DD) + rem;
            *reinterpret_cast<s16x4*>(Kall + de) = h;
        }
    }
}

// ---------------- transpose-cast W[k][n] -> WT[n][k] bf16 hi/lo
__global__ void k_transW(const float* __restrict__ Wq, const float* __restrict__ Wk,
                         const float* __restrict__ Wv,
                         unsigned short* __restrict__ WhT, unsigned short* __restrict__ WlT) {
    __shared__ float t[64][68];
    int z = blockIdx.z;
    const float* W = (z == 0) ? Wq : ((z == 1) ? Wk : Wv);
    int n0 = blockIdx.x * 64, k0 = blockIdx.y * 64;
    int tc = threadIdx.x & 15, tr = threadIdx.x >> 4;
    for (int i = 0; i < 4; ++i) {
        int r = tr + i * 16;
        f32x4 v = *reinterpret_cast<const f32x4*>(W + (int64_t)(k0 + r) * NN + n0 + tc * 4);
        t[r][tc * 4 + 0] = v[0]; t[r][tc * 4 + 1] = v[1];
        t[r][tc * 4 + 2] = v[2]; t[r][tc * 4 + 3] = v[3];
    }
    __syncthreads();
    int64_t zoff = (int64_t)z * MM * NN;
    for (int i = 0; i < 4; ++i) {
        int rr = tr + i * 16;
        s16x4 h, l;
        for (int j = 0; j < 4; ++j) {
            float f = t[tc * 4 + j][rr];
            unsigned short hb = f2bf(f);
            h[j] = (short)hb;
            l[j] = (short)f2bf(f - bf2f(hb));
        }
        *reinterpret_cast<s16x4*>(WhT + zoff + (int64_t)(n0 + rr) * NN + k0 + tc * 4) = h;
        *reinterpret_cast<s16x4*>(WlT + zoff + (int64_t)(n0 + rr) * NN + k0 + tc * 4) = l;
    }
}

// ---------------- projection GEMM: C = Xh*Wh + Xh*Wl + Xl*Wh (split-bf16, ~f32 accurate)
// z=0 -> Qh/Ql (hi/lo bf16), z=1 -> K_all rows P.., z=2 -> Vproj
__launch_bounds__(256)
__global__ void k_gemm(const unsigned short* __restrict__ Xh, const unsigned short* __restrict__ Xl,
                       const unsigned short* __restrict__ WhT, const unsigned short* __restrict__ WlT,
                       unsigned short* __restrict__ Qh, unsigned short* __restrict__ Ql,
                       unsigned short* __restrict__ Kall, unsigned short* __restrict__ Vproj) {
    __shared__ unsigned short sb[2 * 128 * 72];
    unsigned short* As = sb;
    unsigned short* Bs = sb + 128 * 72;
    int z = blockIdx.z;
    int n0 = blockIdx.x * 128, m0 = blockIdx.y * 128;
    int tid = threadIdx.x, lane = tid & 63, wave = tid >> 6;
    int lrow = lane & 15, lgrp = lane >> 4;
    int wm = (wave >> 1) * 64, wn = (wave & 1) * 64;
    f32x4 acc[4][4] = {};
    for (int seg = 0; seg < 3; ++seg) {
        const unsigned short* Asrc = (seg == 2) ? Xl : Xh;
        const unsigned short* Bsrc = ((seg == 1) ? WlT : WhT) + (int64_t)z * MM * NN;
        for (int kt = 0; kt < 16; ++kt) {
            int kb = kt * 64;
            for (int i = 0; i < 4; ++i) {
                int idx = i * 256 + tid;
                int r = idx >> 3, c8 = (idx & 7) * 8;
                *reinterpret_cast<s16x8*>(&As[r * 72 + c8]) =
                    *reinterpret_cast<const s16x8*>(Asrc + (int64_t)(m0 + r) * NN + kb + c8);
                *reinterpret_cast<s16x8*>(&Bs[r * 72 + c8]) =
                    *reinterpret_cast<const s16x8*>(Bsrc + (int64_t)(n0 + r) * NN + kb + c8);
            }
            __syncthreads();
            for (int ks = 0; ks < 2; ++ks) {
                s16x8 af[4], bfr[4];
                for (int f = 0; f < 4; ++f)
                    af[f] = *reinterpret_cast<const s16x8*>(&As[(wm + f * 16 + lrow) * 72 + ks * 32 + lgrp * 8]);
                for (int f = 0; f < 4; ++f)
                    bfr[f] = *reinterpret_cast<const s16x8*>(&Bs[(wn + f * 16 + lrow) * 72 + ks * 32 + lgrp * 8]);
                for (int i = 0; i < 4; ++i)
                    for (int j = 0; j < 4; ++j)
                        acc[i][j] = mfma16(af[i], bfr[j], acc[i][j]);
            }
            __syncthreads();
        }
    }
    unsigned short* Cs = sb;   // reuse staging LDS, pitch 136
    auto stageC = [&](int lo) {
        for (int i = 0; i < 4; ++i)
            for (int j = 0; j < 4; ++j)
                for (int r = 0; r < 4; ++r) {
                    float v = acc[i][j][r];
                    unsigned short hv = f2bf(v);
                    if (lo) hv = f2bf(v - bf2f(hv));
                    Cs[(wm + i * 16 + lgrp * 4 + r) * 136 + wn + j * 16 + lrow] = hv;
                }
    };
    auto writeC = [&](unsigned short* dst, int kmode) {
        for (int i = 0; i < 8; ++i) {
            int idx = i * 256 + tid;
            int r = idx >> 4, c8 = (idx & 15) * 8;
            s16x8 v = *reinterpret_cast<const s16x8*>(&Cs[r * 136 + c8]);
            int gm = m0 + r, gn = n0 + c8;
            if (kmode) {
                int hh = gn >> 6, d = gn & 63;
                *reinterpret_cast<s16x8*>(dst + ((int64_t)hh * LL + PP + gm) * DD + d) = v;
            } else {
                *reinterpret_cast<s16x8*>(dst + (int64_t)gm * NN + gn) = v;
            }
        }
    };
    __syncthreads();
    if (z == 0) {
        stageC(0); __syncthreads(); writeC(Qh, 0);
        __syncthreads(); stageC(1); __syncthreads(); writeC(Ql, 0);
    } else if (z == 1) {
        stageC(0); __syncthreads(); writeC(Kall, 1);
    } else {
        stageC(0); __syncthreads(); writeC(Vproj, 0);
    }
}

// ---------------- V transpose: cache_V (f32) + Vproj (bf16) -> VT[h][d][l] bf16
__global__ void k_transV(const float* __restrict__ cV, const unsigned short* __restrict__ Vproj,
                         unsigned short* __restrict__ VT) {
    __shared__ unsigned short Ts[64][72];
    int b = blockIdx.x;
    int hh = b / 80, lt = b % 80;
    int l0 = lt * 64;
    int tid = threadIdx.x;
    if (l0 < PP) {
        for (int i = 0; i < 4; ++i) {
            int idx = i * 256 + tid;
            int r = idx >> 4, c4 = (idx & 15) * 4;
            f32x4 v = *reinterpret_cast<const f32x4*>(cV + ((int64_t)hh * PP + l0 + r) * DD + c4);
            s16x4 o;
            for (int j = 0; j < 4; ++j) o[j] = (short)f2bf(v[j]);
            *reinterpret_cast<s16x4*>(&Ts[r][c4]) = o;
        }
    } else {
        for (int i = 0; i < 2; ++i) {
            int idx = i * 256 + tid;
            int r = idx >> 3, c8 = (idx & 7) * 8;
            *reinterpret_cast<s16x8*>(&Ts[r][c8]) =
                *reinterpret_cast<const s16x8*>(Vproj + (int64_t)(l0 - PP + r) * NN + hh * DD + c8);
        }
    }
    __syncthreads();
    for (int i = 0; i < 2; ++i) {
        int idx = i * 256 + tid;
        int d = idx >> 3, l8 = (idx & 7) * 8;
        s16x8 v;
        for (int j = 0; j < 8; ++j) v[j] = (short)Ts[l8 + j][d];
        *reinterpret_cast<s16x8*>(VT + ((int64_t)hh * DD + d) * LL + l0 + l8) = v;
    }
}

// ---------------- fused attention + keyformer
// block = (h, 32 q-rows), 4 waves; wave w owns l-columns [c*256 + w*64, +64) of each chunk
__launch_bounds__(256, 2)
__global__ void k_attn(const unsigned short* __restrict__ Qh, const unsigned short* __restrict__ Ql,
                       const unsigned short* __restrict__ Kall, const unsigned short* __restrict__ VT,
                       const float* __restrict__ noise,
                       float* __restrict__ outO, float* __restrict__ outW, float* __restrict__ outP) {
    __shared__ unsigned short wls[32][264];
    __shared__ float red[4][32][4];
    __shared__ float stats[32][4];
    __shared__ float ored[4][64][33];

    int hh = blockIdx.y, m0 = blockIdx.x * 32;
    int tid = threadIdx.x, lane = tid & 63, wave = tid >> 6;
    int lrow = lane & 15, lgrp = lane >> 4;

    s16x8 aqh[2][2], aql[2][2];
    for (int mf = 0; mf < 2; ++mf)
        for (int ks = 0; ks < 2; ++ks) {
            int64_t off = (int64_t)(m0 + mf * 16 + lrow) * NN + hh * DD + ks * 32 + lgrp * 8;
            aqh[mf][ks] = *reinterpret_cast<const s16x8*>(Qh + off);
            aql[mf][ks] = *reinterpret_cast<const s16x8*>(Ql + off);
        }

    const unsigned short* Kh = Kall + (int64_t)hh * LL * DD;
    const unsigned short* Vh = VT + (int64_t)hh * DD * LL;
    const float* nzb = noise + (int64_t)hh * MM * LL + (int64_t)m0 * LL;

    float mw[8], sw[8], mp[8], sp[8];
    for (int s = 0; s < 8; ++s) { mw[s] = -3.0e38f; sw[s] = 0.f; mp[s] = -3.0e38f; sp[s] = 0.f; }

    // ---- phase 1: stats
    for (int c = 0; c < 20; ++c) {
        int lbase = c * 256 + wave * 64;
        f32x4 sacc[2][4] = {};
        for (int ks = 0; ks < 2; ++ks)
            for (int lf = 0; lf < 4; ++lf) {
                s16x8 bk = *reinterpret_cast<const s16x8*>(
                    Kh + (int64_t)(lbase + lf * 16 + lrow) * DD + ks * 32 + lgrp * 8);
                sacc[0][lf] = mfma16(aqh[0][ks], bk, sacc[0][lf]);
                sacc[0][lf] = mfma16(aql[0][ks], bk, sacc[0][lf]);
                sacc[1][lf] = mfma16(aqh[1][ks], bk, sacc[1][lf]);
                sacc[1][lf] = mfma16(aql[1][ks], bk, sacc[1][lf]);
            }
        for (int mf = 0; mf < 2; ++mf)
            for (int r = 0; r < 4; ++r) {
                int s = mf * 4 + r;
                int row = mf * 16 + lgrp * 4 + r;
                float v0 = sacc[mf][0][r], v1 = sacc[mf][1][r], v2 = sacc[mf][2][r], v3 = sacc[mf][3][r];
                float mx = fmaxf(fmaxf(v0, v1), fmaxf(v2, v3));
                float nm = fmaxf(mw[s], mx);
                sw[s] = sw[s] * __expf(mw[s] - nm) +
                        __expf(v0 - nm) + __expf(v1 - nm) + __expf(v2 - nm) + __expf(v3 - nm);
                mw[s] = nm;
                const float* nrow = nzb + (int64_t)row * LL + lbase + lrow;
                float t0 = (v0 + nrow[0])  * (1.f / 1.5f);
                float t1 = (v1 + nrow[16]) * (1.f / 1.5f);
                float t2 = (v2 + nrow[32]) * (1.f / 1.5f);
                float t3 = (v3 + nrow[48]) * (1.f / 1.5f);
                float mx2 = fmaxf(fmaxf(t0, t1), fmaxf(t2, t3));
                float nm2 = fmaxf(mp[s], mx2);
                sp[s] = sp[s] * __expf(mp[s] - nm2) +
                        __expf(t0 - nm2) + __expf(t1 - nm2) + __expf(t2 - nm2) + __expf(t3 - nm2);
                mp[s] = nm2;
            }
    }
    // reduce across 16 lanes (columns) within each row group
    for (int s = 0; s < 8; ++s) {
        for (int d = 1; d < 16; d <<= 1) {
            float om = __shfl_xor(mw[s], d, 64);
            float os = __shfl_xor(sw[s], d, 64);
            float nm = fmaxf(mw[s], om);
            sw[s] = sw[s] * __expf(mw[s] - nm) + os * __expf(om - nm);
            mw[s] = nm;
            om = __shfl_xor(mp[s], d, 64);
            os = __shfl_xor(sp[s], d, 64);
            nm = fmaxf(mp[s], om);
            sp[s] = sp[s] * __expf(mp[s] - nm) + os * __expf(om - nm);
            mp[s] = nm;
        }
    }
    if (lrow == 0) {
        for (int s = 0; s < 8; ++s) {
            int mf = s >> 2, r = s & 3;
            int row = mf * 16 + lgrp * 4 + r;
            red[wave][row][0] = mw[s]; red[wave][row][1] = sw[s];
            red[wave][row][2] = mp[s]; red[wave][row][3] = sp[s];
        }
    }
    __syncthreads();
    if (tid < 64) {
        int row = tid >> 1, ty = (tid & 1) * 2;
        float Mx = red[0][row][ty], S = red[0][row][ty + 1];
        for (int w2 = 1; w2 < 4; ++w2) {
            float om = red[w2][row][ty], os = red[w2][row][ty + 1];
            float nm = fmaxf(Mx, om);
            S = S * __expf(Mx - nm) + os * __expf(om - nm);
            Mx = nm;
        }
        stats[row][ty] = Mx; stats[row][ty + 1] = 1.0f / S;
    }
    __syncthreads();
    for (int s = 0; s < 8; ++s) {
        int mf = s >> 2, r = s & 3;
        int row = mf * 16 + lgrp * 4 + r;
        mw[s] = stats[row][0]; sw[s] = stats[row][1];   // sw now inv_sum
        mp[s] = stats[row][2]; sp[s] = stats[row][3];
    }

    // ---- phase 2: emit weights/perturb, accumulate O^T = V^T * W^T
    f32x4 oacc[4][2] = {};
    float* outWb = outW + (int64_t)hh * MM * LL + (int64_t)m0 * LL;
    float* outPb = outP + (int64_t)hh * MM * LL + (int64_t)m0 * LL;

    for (int c = 0; c < 20; ++c) {
        int lbase = c * 256 + wave * 64;
        f32x4 sacc[2][4] = {};
        for (int ks = 0; ks < 2; ++ks)
            for (int lf = 0; lf < 4; ++lf) {
                s16x8 bk = *reinterpret_cast<const s16x8*>(
                    Kh + (int64_t)(lbase + lf * 16 + lrow) * DD + ks * 32 + lgrp * 8);
                sacc[0][lf] = mfma16(aqh[0][ks], bk, sacc[0][lf]);
                sacc[0][lf] = mfma16(aql[0][ks], bk, sacc[0][lf]);
                sacc[1][lf] = mfma16(aqh[1][ks], bk, sacc[1][lf]);
                sacc[1][lf] = mfma16(aql[1][ks], bk, sacc[1][lf]);
            }
        for (int mf = 0; mf < 2; ++mf)
            for (int r = 0; r < 4; ++r) {
                int s = mf * 4 + r;
                int row = mf * 16 + lgrp * 4 + r;
                const float* nrow = nzb + (int64_t)row * LL + lbase + lrow;
                float* wrow = outWb + (int64_t)row * LL + lbase + lrow;
                float* prow = outPb + (int64_t)row * LL + lbase + lrow;
                for (int lf = 0; lf < 4; ++lf) {
                    float v = sacc[mf][lf][r];
                    float w = __expf(v - mw[s]) * sw[s];
                    wrow[lf * 16] = w;
                    wls[row][wave * 64 + lf * 16 + lrow] = f2bf(w);
                    float t = (v + nrow[lf * 16]) * (1.f / 1.5f);
                    prow[lf * 16] = __expf(t - mp[s]) * sp[s];
                }
            }
        __syncthreads();
        for (int ks = 0; ks < 2; ++ks) {
            int k0 = wave * 64 + ks * 32;
            s16x8 bw0 = *reinterpret_cast<const s16x8*>(&wls[lrow][k0 + lgrp * 8]);
            s16x8 bw1 = *reinterpret_cast<const s16x8*>(&wls[16 + lrow][k0 + lgrp * 8]);
            for (int df = 0; df < 4; ++df) {
                s16x8 av = *reinterpret_cast<const s16x8*>(
                    Vh + (int64_t)(df * 16 + lrow) * LL + c * 256 + k0 + lgrp * 8);
                oacc[df][0] = mfma16(av, bw0, oacc[df][0]);
                oacc[df][1] = mfma16(av, bw1, oacc[df][1]);
            }
        }
        __syncthreads();
    }
    // cross-wave reduce of O^T partials, write output [m][h*64+d]
    for (int df = 0; df < 4; ++df)
        for (int mf = 0; mf < 2; ++mf)
            for (int r = 0; r < 4; ++r)
                ored[wave][df * 16 + lgrp * 4 + r][mf * 16 + lrow] = oacc[df][mf][r];
    __syncthreads();
    for (int i = 0; i < 8; ++i) {
        int idx = i * 256 + tid;
        int d = idx & 63, m = idx >> 6;
        float v = ored[0][d][m] + ored[1][d][m] + ored[2][d][m] + ored[3][d][m];
        outO[(int64_t)(m0 + m) * NN + hh * DD + d] = v;
    }
}

extern "C" void kernel_launch(void* const* d_in, const int* in_sizes, int n_in,
                              void* d_out, int out_size, void* d_ws, size_t ws_size,
                              hipStream_t stream) {
    const float* X  = (const float*)d_in[0];
    const float* Wq = (const float*)d_in[1];
    const float* Wk = (const float*)d_in[2];
    const float* Wv = (const float*)d_in[3];
    const float* cK = (const float*)d_in[4];
    const float* cV = (const float*)d_in[5];
    const float* nz = (const float*)d_in[6];

    char* ws = (char*)d_ws;
    const int64_t U = 1 << 21;   // 2 MB units
    unsigned short* Xh    = (unsigned short*)(ws + 0 * U);
    unsigned short* Xl    = (unsigned short*)(ws + 1 * U);
    unsigned short* WhT   = (unsigned short*)(ws + 2 * U);   // 3 units
    unsigned short* WlT   = (unsigned short*)(ws + 5 * U);   // 3 units
    unsigned short* Qh    = (unsigned short*)(ws + 8 * U);
    unsigned short* Ql    = (unsigned short*)(ws + 9 * U);
    unsigned short* Kall  = (unsigned short*)(ws + 10 * U);  // 5 units (16*5120*64 bf16)
    unsigned short* Vproj = (unsigned short*)(ws + 15 * U);
    unsigned short* VT    = (unsigned short*)(ws + 16 * U);  // 5 units

    float* outO = (float*)d_out;
    float* outW = outO + (int64_t)MM * NN;
    float* outP = outW + (int64_t)HH * MM * LL;

    k_prep<<<2048, 256, 0, stream>>>(X, cK, Xh, Xl, Kall);
    k_transW<<<dim3(16, 16, 3), 256, 0, stream>>>(Wq, Wk, Wv, WhT, WlT);
    k_gemm<<<dim3(8, 8, 3), 256, 0, stream>>>(Xh, Xl, WhT, WlT, Qh, Ql, Kall, Vproj);
    k_transV<<<1280, 256, 0, stream>>>(cV, Vproj, VT);
    k_attn<<<dim3(32, 16), 256, 0, stream>>>(Qh, Ql, Kall, VT, nz, outO, outW, outP);
}

// Round 2
// 966.155 us; speedup vs baseline: 1.0644x; 1.0644x over previous
//
#include <hip/hip_runtime.h>
#include <stdint.h>

#define MM 1024
#define NN 1024
#define DD 64
#define PP 4096
#define HH 16
#define LL 5120   // P + M
#define SHC 12.0f

typedef float  f32x4  __attribute__((ext_vector_type(4)));
typedef short  s16x8  __attribute__((ext_vector_type(8)));
typedef short  s16x4  __attribute__((ext_vector_type(4)));
typedef __bf16 bf16x8 __attribute__((ext_vector_type(8)));

static __device__ __forceinline__ unsigned short f2bf(float f) {
    unsigned u = __float_as_uint(f);
    u += 0x7FFFu + ((u >> 16) & 1u);   // RNE (no NaNs in this workload)
    return (unsigned short)(u >> 16);
}
static __device__ __forceinline__ float bf2f(unsigned short h) {
    return __uint_as_float(((unsigned)h) << 16);
}
static __device__ __forceinline__ f32x4 mfma16(s16x8 a, s16x8 b, f32x4 c) {
    return __builtin_amdgcn_mfma_f32_16x16x32_bf16(
        __builtin_bit_cast(bf16x8, a), __builtin_bit_cast(bf16x8, b), c, 0, 0, 0);
}

// ---------------- prep: cast X -> (Xh, Xl) bf16 split; cast cache_K into K_all[h][0..P-1][d]
__global__ void k_prep(const float* __restrict__ X, const float* __restrict__ cK,
                       unsigned short* __restrict__ Xh, unsigned short* __restrict__ Xl,
                       unsigned short* __restrict__ Kall) {
    const int nX4 = (MM * NN) / 4;        // 262144
    const int nK4 = (HH * PP * DD) / 4;   // 1048576
    int stride = gridDim.x * blockDim.x;
    for (int i = blockIdx.x * blockDim.x + threadIdx.x; i < nX4 + nK4; i += stride) {
        if (i < nX4) {
            f32x4 v = reinterpret_cast<const f32x4*>(X)[i];
            s16x4 h, l;
            for (int j = 0; j < 4; ++j) {
                float f = v[j];
                unsigned short hb = f2bf(f);
                h[j] = (short)hb;
                l[j] = (short)f2bf(f - bf2f(hb));
            }
            reinterpret_cast<s16x4*>(Xh)[i] = h;
            reinterpret_cast<s16x4*>(Xl)[i] = l;
        } else {
            int j = i - nX4;
            f32x4 v = reinterpret_cast<const f32x4*>(cK)[j];
            s16x4 h;
            for (int jj = 0; jj < 4; ++jj) h[jj] = (short)f2bf(v[jj]);
            int e = j * 4;
            int hh = e >> 18;              // P*D = 262144 = 2^18
            int rem = e & 262143;
            int64_t de = (int64_t)hh * (LL * DD) + rem;
            *reinterpret_cast<s16x4*>(Kall + de) = h;
        }
    }
}

// ---------------- transpose-cast W[k][n] -> WT[n][k] bf16 hi/lo
__global__ void k_transW(const float* __restrict__ Wq, const float* __restrict__ Wk,
                         const float* __restrict__ Wv,
                         unsigned short* __restrict__ WhT, unsigned short* __restrict__ WlT) {
    __shared__ float t[64][68];
    int z = blockIdx.z;
    const float* W = (z == 0) ? Wq : ((z == 1) ? Wk : Wv);
    int n0 = blockIdx.x * 64, k0 = blockIdx.y * 64;
    int tc = threadIdx.x & 15, tr = threadIdx.x >> 4;
    for (int i = 0; i < 4; ++i) {
        int r = tr + i * 16;
        f32x4 v = *reinterpret_cast<const f32x4*>(W + (int64_t)(k0 + r) * NN + n0 + tc * 4);
        t[r][tc * 4 + 0] = v[0]; t[r][tc * 4 + 1] = v[1];
        t[r][tc * 4 + 2] = v[2]; t[r][tc * 4 + 3] = v[3];
    }
    __syncthreads();
    int64_t zoff = (int64_t)z * MM * NN;
    for (int i = 0; i < 4; ++i) {
        int rr = tr + i * 16;
        s16x4 h, l;
        for (int j = 0; j < 4; ++j) {
            float f = t[tc * 4 + j][rr];
            unsigned short hb = f2bf(f);
            h[j] = (short)hb;
            l[j] = (short)f2bf(f - bf2f(hb));
        }
        *reinterpret_cast<s16x4*>(WhT + zoff + (int64_t)(n0 + rr) * NN + k0 + tc * 4) = h;
        *reinterpret_cast<s16x4*>(WlT + zoff + (int64_t)(n0 + rr) * NN + k0 + tc * 4) = l;
    }
}

// ---------------- projection GEMM: C = Xh*Wh + Xh*Wl + Xl*Wh (split-bf16, ~f32 accurate)
__launch_bounds__(256)
__global__ void k_gemm(const unsigned short* __restrict__ Xh, const unsigned short* __restrict__ Xl,
                       const unsigned short* __restrict__ WhT, const unsigned short* __restrict__ WlT,
                       unsigned short* __restrict__ Qh, unsigned short* __restrict__ Ql,
                       unsigned short* __restrict__ Kall, unsigned short* __restrict__ Vproj) {
    __shared__ unsigned short sb[2 * 128 * 72];
    unsigned short* As = sb;
    unsigned short* Bs = sb + 128 * 72;
    int z = blockIdx.z;
    int n0 = blockIdx.x * 128, m0 = blockIdx.y * 128;
    int tid = threadIdx.x, lane = tid & 63, wave = tid >> 6;
    int lrow = lane & 15, lgrp = lane >> 4;
    int wm = (wave >> 1) * 64, wn = (wave & 1) * 64;
    f32x4 acc[4][4] = {};
    for (int seg = 0; seg < 3; ++seg) {
        const unsigned short* Asrc = (seg == 2) ? Xl : Xh;
        const unsigned short* Bsrc = ((seg == 1) ? WlT : WhT) + (int64_t)z * MM * NN;
        for (int kt = 0; kt < 16; ++kt) {
            int kb = kt * 64;
            for (int i = 0; i < 4; ++i) {
                int idx = i * 256 + tid;
                int r = idx >> 3, c8 = (idx & 7) * 8;
                *reinterpret_cast<s16x8*>(&As[r * 72 + c8]) =
                    *reinterpret_cast<const s16x8*>(Asrc + (int64_t)(m0 + r) * NN + kb + c8);
                *reinterpret_cast<s16x8*>(&Bs[r * 72 + c8]) =
                    *reinterpret_cast<const s16x8*>(Bsrc + (int64_t)(n0 + r) * NN + kb + c8);
            }
            __syncthreads();
            for (int ks = 0; ks < 2; ++ks) {
                s16x8 af[4], bfr[4];
                for (int f = 0; f < 4; ++f)
                    af[f] = *reinterpret_cast<const s16x8*>(&As[(wm + f * 16 + lrow) * 72 + ks * 32 + lgrp * 8]);
                for (int f = 0; f < 4; ++f)
                    bfr[f] = *reinterpret_cast<const s16x8*>(&Bs[(wn + f * 16 + lrow) * 72 + ks * 32 + lgrp * 8]);
                for (int i = 0; i < 4; ++i)
                    for (int j = 0; j < 4; ++j)
                        acc[i][j] = mfma16(af[i], bfr[j], acc[i][j]);
            }
            __syncthreads();
        }
    }
    unsigned short* Cs = sb;   // reuse staging LDS, pitch 136
    auto stageC = [&](int lo) {
        for (int i = 0; i < 4; ++i)
            for (int j = 0; j < 4; ++j)
                for (int r = 0; r < 4; ++r) {
                    float v = acc[i][j][r];
                    unsigned short hv = f2bf(v);
                    if (lo) hv = f2bf(v - bf2f(hv));
                    Cs[(wm + i * 16 + lgrp * 4 + r) * 136 + wn + j * 16 + lrow] = hv;
                }
    };
    auto writeC = [&](unsigned short* dst, int kmode) {
        for (int i = 0; i < 8; ++i) {
            int idx = i * 256 + tid;
            int r = idx >> 4, c8 = (idx & 15) * 8;
            s16x8 v = *reinterpret_cast<const s16x8*>(&Cs[r * 136 + c8]);
            int gm = m0 + r, gn = n0 + c8;
            if (kmode) {
                int hh = gn >> 6, d = gn & 63;
                *reinterpret_cast<s16x8*>(dst + ((int64_t)hh * LL + PP + gm) * DD + d) = v;
            } else {
                *reinterpret_cast<s16x8*>(dst + (int64_t)gm * NN + gn) = v;
            }
        }
    };
    __syncthreads();
    if (z == 0) {
        stageC(0); __syncthreads(); writeC(Qh, 0);
        __syncthreads(); stageC(1); __syncthreads(); writeC(Ql, 0);
    } else if (z == 1) {
        stageC(0); __syncthreads(); writeC(Kall, 1);
    } else {
        stageC(0); __syncthreads(); writeC(Vproj, 0);
    }
}

// ---------------- V transpose: cache_V (f32) + Vproj (bf16) -> VT[h][d][l] bf16
__global__ void k_transV(const float* __restrict__ cV, const unsigned short* __restrict__ Vproj,
                         unsigned short* __restrict__ VT) {
    __shared__ unsigned short Ts[64][72];
    int b = blockIdx.x;
    int hh = b / 80, lt = b % 80;
    int l0 = lt * 64;
    int tid = threadIdx.x;
    if (l0 < PP) {
        for (int i = 0; i < 4; ++i) {
            int idx = i * 256 + tid;
            int r = idx >> 4, c4 = (idx & 15) * 4;
            f32x4 v = *reinterpret_cast<const f32x4*>(cV + ((int64_t)hh * PP + l0 + r) * DD + c4);
            s16x4 o;
            for (int j = 0; j < 4; ++j) o[j] = (short)f2bf(v[j]);
            *reinterpret_cast<s16x4*>(&Ts[r][c4]) = o;
        }
    } else {
        for (int i = 0; i < 2; ++i) {
            int idx = i * 256 + tid;
            int r = idx >> 3, c8 = (idx & 7) * 8;
            *reinterpret_cast<s16x8*>(&Ts[r][c8]) =
                *reinterpret_cast<const s16x8*>(Vproj + (int64_t)(l0 - PP + r) * NN + hh * DD + c8);
        }
    }
    __syncthreads();
    for (int i = 0; i < 2; ++i) {
        int idx = i * 256 + tid;
        int d = idx >> 3, l8 = (idx & 7) * 8;
        s16x8 v;
        for (int j = 0; j < 8; ++j) v[j] = (short)Ts[l8 + j][d];
        *reinterpret_cast<s16x8*>(VT + ((int64_t)hh * DD + d) * LL + l0 + l8) = v;
    }
}

// ---------------- single-pass attention: unnormalized W/P emit + partial sums + partial O
// grid (Lq=2, mt=64, h=16); block 256 = 4 waves; each block: 16 q-rows x 2560 l-cols
__launch_bounds__(256, 4)
__global__ void k_attnA(const unsigned short* __restrict__ Qh, const unsigned short* __restrict__ Ql,
                        const unsigned short* __restrict__ Kall, const unsigned short* __restrict__ VT,
                        const float* __restrict__ noise,
                        float* __restrict__ outW, float* __restrict__ outP,
                        float* __restrict__ wsO, float* __restrict__ wsS) {
    __shared__ float sc[16][272];            // scores staging; aliased as ored at the end
    __shared__ unsigned short wls[16][264];  // bf16 unnormalized weights for PV

    int hh = blockIdx.z, mt = blockIdx.y, Lq = blockIdx.x;
    int m0 = mt * 16;
    int tid = threadIdx.x, lane = tid & 63, wave = tid >> 6;
    int lrow = lane & 15, lgrp = lane >> 4;
    int erow = tid >> 4, cb = tid & 15;      // emit: fixed row per thread

    s16x8 aqh[2], aql[2];
    for (int ks = 0; ks < 2; ++ks) {
        int64_t off = (int64_t)(m0 + lrow) * NN + hh * DD + ks * 32 + lgrp * 8;
        aqh[ks] = *reinterpret_cast<const s16x8*>(Qh + off);
        aql[ks] = *reinterpret_cast<const s16x8*>(Ql + off);
    }
    const unsigned short* Kh = Kall + (int64_t)hh * LL * DD;
    const unsigned short* Vh = VT + (int64_t)hh * DD * LL;
    const float* nzr = noise + ((int64_t)hh * MM + m0 + erow) * LL;
    float* Wr = outW + ((int64_t)hh * MM + m0 + erow) * LL;
    float* Pr = outP + ((int64_t)hh * MM + m0 + erow) * LL;

    float Sw = 0.f, Sp = 0.f;
    f32x4 oacc[4] = {};

    for (int c = 0; c < 10; ++c) {
        int c0 = (Lq * 10 + c) * 256;
        // --- QK^T (hi/lo split Q) + stage scores to LDS
        {
            f32x4 sacc[4] = {};
            int lb = c0 + wave * 64;
            for (int ks = 0; ks < 2; ++ks)
                for (int lf = 0; lf < 4; ++lf) {
                    s16x8 bk = *reinterpret_cast<const s16x8*>(
                        Kh + (int64_t)(lb + lf * 16 + lrow) * DD + ks * 32 + lgrp * 8);
                    sacc[lf] = mfma16(aqh[ks], bk, sacc[lf]);
                    sacc[lf] = mfma16(aql[ks], bk, sacc[lf]);
                }
            for (int lf = 0; lf < 4; ++lf)
                for (int r = 0; r < 4; ++r)
                    sc[lgrp * 4 + r][wave * 64 + lf * 16 + lrow] = sacc[lf][r];
        }
        __syncthreads();
        // --- coalesced emit: unnormalized exp values, running sums, bf16 pack for PV
        for (int q = 0; q < 4; ++q) {
            int col = q * 64 + cb * 4;
            f32x4 s = *reinterpret_cast<const f32x4*>(&sc[erow][col]);
            f32x4 nv = *reinterpret_cast<const f32x4*>(nzr + c0 + col);
            f32x4 wv, pv;
            for (int j = 0; j < 4; ++j) {
                wv[j] = __expf(s[j] - SHC);
                pv[j] = __expf((s[j] + nv[j]) * (1.f / 1.5f) - SHC);
            }
            *reinterpret_cast<f32x4*>(Wr + c0 + col) = wv;
            *reinterpret_cast<f32x4*>(Pr + c0 + col) = pv;
            Sw += wv[0] + wv[1] + wv[2] + wv[3];
            Sp += pv[0] + pv[1] + pv[2] + pv[3];
            s16x4 pk;
            for (int j = 0; j < 4; ++j) pk[j] = (short)f2bf(wv[j]);
            *reinterpret_cast<s16x4*>(&wls[erow][col]) = pk;
        }
        __syncthreads();
        // --- PV: O^T += V^T * W^T (unnormalized)
        for (int ks = 0; ks < 2; ++ks) {
            int k0 = wave * 64 + ks * 32;
            s16x8 bw = *reinterpret_cast<const s16x8*>(&wls[lrow][k0 + lgrp * 8]);
            for (int df = 0; df < 4; ++df) {
                s16x8 av = *reinterpret_cast<const s16x8*>(
                    Vh + (int64_t)(df * 16 + lrow) * LL + c0 + k0 + lgrp * 8);
                oacc[df] = mfma16(av, bw, oacc[df]);
            }
        }
    }
    // --- row-sum reduce across the 16 lanes sharing a row
    for (int d = 1; d < 16; d <<= 1) {
        Sw += __shfl_xor(Sw, d, 64);
        Sp += __shfl_xor(Sp, d, 64);
    }
    if (cb == 0) {
        int sbase = (((hh * 64 + mt) * 2 + Lq) * 16 + erow) * 2;
        wsS[sbase] = Sw;
        wsS[sbase + 1] = Sp;
    }
    // --- cross-wave O^T reduce via LDS (aliases sc), write partial O to ws
    float* ored = &sc[0][0];   // [4][64][17]
    for (int df = 0; df < 4; ++df)
        for (int r = 0; r < 4; ++r)
            ored[(wave * 64 + df * 16 + lgrp * 4 + r) * 17 + lrow] = oacc[df][r];
    __syncthreads();
    int obase = ((hh * 64 + mt) * 2 + Lq) * 1024;
    for (int i = 0; i < 4; ++i) {
        int idx = i * 256 + tid;
        int m = idx >> 6, d = idx & 63;
        wsO[obase + m * 64 + d] = ored[d * 17 + m] + ored[(64 + d) * 17 + m] +
                                  ored[(128 + d) * 17 + m] + ored[(192 + d) * 17 + m];
    }
}

// ---------------- rescale W/P by global row sums (pure streaming)
__global__ void k_rescale(float* __restrict__ outW, float* __restrict__ outP,
                          const float* __restrict__ wsS) {
    int bid = blockIdx.x;                 // 16384 = h*1024 + m
    int hh = bid >> 10, m = bid & 1023;
    int mt = m >> 4, row = m & 15;
    int b0 = (((hh * 64 + mt) * 2 + 0) * 16 + row) * 2;
    int b1 = (((hh * 64 + mt) * 2 + 1) * 16 + row) * 2;
    float iw = 1.f / (wsS[b0] + wsS[b1]);
    float ip = 1.f / (wsS[b0 + 1] + wsS[b1 + 1]);
    float* Wr = outW + ((int64_t)hh * MM + m) * LL;
    float* Pr = outP + ((int64_t)hh * MM + m) * LL;
    for (int i = threadIdx.x * 4; i < LL; i += 1024) {
        f32x4 w = *reinterpret_cast<const f32x4*>(Wr + i);
        f32x4 p = *reinterpret_cast<const f32x4*>(Pr + i);
        for (int j = 0; j < 4; ++j) { w[j] *= iw; p[j] *= ip; }
        *reinterpret_cast<f32x4*>(Wr + i) = w;
        *reinterpret_cast<f32x4*>(Pr + i) = p;
    }
}

// ---------------- finalize O: combine 2 partials, scale, write [m][h*64+d]
__global__ void k_ofinal(const float* __restrict__ wsO, const float* __restrict__ wsS,
                         float* __restrict__ outO) {
    int bid = blockIdx.x;                 // 1024 = h*64 + mt
    int hh = bid >> 6, mt = bid & 63;
    int row = threadIdx.x >> 4, d0 = (threadIdx.x & 15) * 4;
    int sb0 = (((hh * 64 + mt) * 2 + 0) * 16 + row) * 2;
    int sb1 = (((hh * 64 + mt) * 2 + 1) * 16 + row) * 2;
    float iw = 1.f / (wsS[sb0] + wsS[sb1]);
    int o0 = ((hh * 64 + mt) * 2 + 0) * 1024 + row * 64 + d0;
    int o1 = o0 + 1024;
    f32x4 a = *reinterpret_cast<const f32x4*>(wsO + o0);
    f32x4 b = *reinterpret_cast<const f32x4*>(wsO + o1);
    f32x4 r;
    for (int j = 0; j < 4; ++j) r[j] = (a[j] + b[j]) * iw;
    *reinterpret_cast<f32x4*>(outO + (int64_t)(mt * 16 + row) * NN + hh * DD + d0) = r;
}

extern "C" void kernel_launch(void* const* d_in, const int* in_sizes, int n_in,
                              void* d_out, int out_size, void* d_ws, size_t ws_size,
                              hipStream_t stream) {
    const float* X  = (const float*)d_in[0];
    const float* Wq = (const float*)d_in[1];
    const float* Wk = (const float*)d_in[2];
    const float* Wv = (const float*)d_in[3];
    const float* cK = (const float*)d_in[4];
    const float* cV = (const float*)d_in[5];
    const float* nz = (const float*)d_in[6];

    char* ws = (char*)d_ws;
    const int64_t U = 1 << 21;   // 2 MB units
    unsigned short* Xh    = (unsigned short*)(ws + 0 * U);
    unsigned short* Xl    = (unsigned short*)(ws + 1 * U);
    unsigned short* WhT   = (unsigned short*)(ws + 2 * U);   // 3 units
    unsigned short* WlT   = (unsigned short*)(ws + 5 * U);   // 3 units
    unsigned short* Qh    = (unsigned short*)(ws + 8 * U);
    unsigned short* Ql    = (unsigned short*)(ws + 9 * U);
    unsigned short* Kall  = (unsigned short*)(ws + 10 * U);  // 5 units
    unsigned short* Vproj = (unsigned short*)(ws + 15 * U);
    unsigned short* VT    = (unsigned short*)(ws + 16 * U);  // 5 units
    // dead after k_gemm: units 0-7 -> reuse for attention partials
    float* wsO = (float*)(ws + 0 * U);   // 2048 * 1024 f32 = 8 MB (units 0-3)
    float* wsS = (float*)(ws + 4 * U);   // 64K f32 = 256 KB

    float* outO = (float*)d_out;
    float* outW = outO + (int64_t)MM * NN;
    float* outP = outW + (int64_t)HH * MM * LL;

    k_prep<<<2048, 256, 0, stream>>>(X, cK, Xh, Xl, Kall);
    k_transW<<<dim3(16, 16, 3), 256, 0, stream>>>(Wq, Wk, Wv, WhT, WlT);
    k_gemm<<<dim3(8, 8, 3), 256, 0, stream>>>(Xh, Xl, WhT, WlT, Qh, Ql, Kall, Vproj);
    k_transV<<<1280, 256, 0, stream>>>(cV, Vproj, VT);
    k_attnA<<<dim3(2, 64, 16), 256, 0, stream>>>(Qh, Ql, Kall, VT, nz, outW, outP, wsO, wsS);
    k_rescale<<<16384, 256, 0, stream>>>(outW, outP, wsS);
    k_ofinal<<<1024, 256, 0, stream>>>(wsO, wsS, outO);
}

// Round 4
// 813.149 us; speedup vs baseline: 1.2647x; 1.1882x over previous
//
#include <hip/hip_runtime.h>
#include <stdint.h>

#define MM 1024
#define NN 1024
#define DD 64
#define PP 4096
#define HH 16
#define LL 5120   // P + M
#define SHC 12.0f

typedef float  f32x4  __attribute__((ext_vector_type(4)));
typedef short  s16x8  __attribute__((ext_vector_type(8)));
typedef short  s16x4  __attribute__((ext_vector_type(4)));
typedef __bf16 bf16x8 __attribute__((ext_vector_type(8)));

static __device__ __forceinline__ unsigned short f2bf(float f) {
    unsigned u = __float_as_uint(f);
    u += 0x7FFFu + ((u >> 16) & 1u);   // RNE (no NaNs in this workload)
    return (unsigned short)(u >> 16);
}
static __device__ __forceinline__ float bf2f(unsigned short h) {
    return __uint_as_float(((unsigned)h) << 16);
}
static __device__ __forceinline__ f32x4 mfma16(s16x8 a, s16x8 b, f32x4 c) {
    return __builtin_amdgcn_mfma_f32_16x16x32_bf16(
        __builtin_bit_cast(bf16x8, a), __builtin_bit_cast(bf16x8, b), c, 0, 0, 0);
}

// ---------------- prep: cast X -> (Xh, Xl) bf16 split; cast cache_K into K_all[h][0..P-1][d]
__global__ void k_prep(const float* __restrict__ X, const float* __restrict__ cK,
                       unsigned short* __restrict__ Xh, unsigned short* __restrict__ Xl,
                       unsigned short* __restrict__ Kall) {
    const int nX4 = (MM * NN) / 4;        // 262144
    const int nK4 = (HH * PP * DD) / 4;   // 1048576
    int stride = gridDim.x * blockDim.x;
    for (int i = blockIdx.x * blockDim.x + threadIdx.x; i < nX4 + nK4; i += stride) {
        if (i < nX4) {
            f32x4 v = reinterpret_cast<const f32x4*>(X)[i];
            s16x4 h, l;
            for (int j = 0; j < 4; ++j) {
                float f = v[j];
                unsigned short hb = f2bf(f);
                h[j] = (short)hb;
                l[j] = (short)f2bf(f - bf2f(hb));
            }
            reinterpret_cast<s16x4*>(Xh)[i] = h;
            reinterpret_cast<s16x4*>(Xl)[i] = l;
        } else {
            int j = i - nX4;
            f32x4 v = reinterpret_cast<const f32x4*>(cK)[j];
            s16x4 h;
            for (int jj = 0; jj < 4; ++jj) h[jj] = (short)f2bf(v[jj]);
            int e = j * 4;
            int hh = e >> 18;              // P*D = 262144 = 2^18
            int rem = e & 262143;
            int64_t de = (int64_t)hh * (LL * DD) + rem;
            *reinterpret_cast<s16x4*>(Kall + de) = h;
        }
    }
}

// ---------------- transpose-cast W[k][n] -> WT[n][k] bf16 hi/lo
__global__ void k_transW(const float* __restrict__ Wq, const float* __restrict__ Wk,
                         const float* __restrict__ Wv,
                         unsigned short* __restrict__ WhT, unsigned short* __restrict__ WlT) {
    __shared__ float t[64][68];
    int z = blockIdx.z;
    const float* W = (z == 0) ? Wq : ((z == 1) ? Wk : Wv);
    int n0 = blockIdx.x * 64, k0 = blockIdx.y * 64;
    int tc = threadIdx.x & 15, tr = threadIdx.x >> 4;
    for (int i = 0; i < 4; ++i) {
        int r = tr + i * 16;
        f32x4 v = *reinterpret_cast<const f32x4*>(W + (int64_t)(k0 + r) * NN + n0 + tc * 4);
        t[r][tc * 4 + 0] = v[0]; t[r][tc * 4 + 1] = v[1];
        t[r][tc * 4 + 2] = v[2]; t[r][tc * 4 + 3] = v[3];
    }
    __syncthreads();
    int64_t zoff = (int64_t)z * MM * NN;
    for (int i = 0; i < 4; ++i) {
        int rr = tr + i * 16;
        s16x4 h, l;
        for (int j = 0; j < 4; ++j) {
            float f = t[tc * 4 + j][rr];
            unsigned short hb = f2bf(f);
            h[j] = (short)hb;
            l[j] = (short)f2bf(f - bf2f(hb));
        }
        *reinterpret_cast<s16x4*>(WhT + zoff + (int64_t)(n0 + rr) * NN + k0 + tc * 4) = h;
        *reinterpret_cast<s16x4*>(WlT + zoff + (int64_t)(n0 + rr) * NN + k0 + tc * 4) = l;
    }
}

// ---------------- projection GEMM: C = Xh*Wh + Xh*Wl + Xl*Wh (split-bf16, ~f32 accurate)
__launch_bounds__(256)
__global__ void k_gemm(const unsigned short* __restrict__ Xh, const unsigned short* __restrict__ Xl,
                       const unsigned short* __restrict__ WhT, const unsigned short* __restrict__ WlT,
                       unsigned short* __restrict__ Qh, unsigned short* __restrict__ Ql,
                       unsigned short* __restrict__ Kall, unsigned short* __restrict__ Vproj) {
    __shared__ unsigned short sb[2 * 128 * 72];
    unsigned short* As = sb;
    unsigned short* Bs = sb + 128 * 72;
    int z = blockIdx.z;
    int n0 = blockIdx.x * 128, m0 = blockIdx.y * 128;
    int tid = threadIdx.x, lane = tid & 63, wave = tid >> 6;
    int lrow = lane & 15, lgrp = lane >> 4;
    int wm = (wave >> 1) * 64, wn = (wave & 1) * 64;
    f32x4 acc[4][4] = {};
    for (int seg = 0; seg < 3; ++seg) {
        const unsigned short* Asrc = (seg == 2) ? Xl : Xh;
        const unsigned short* Bsrc = ((seg == 1) ? WlT : WhT) + (int64_t)z * MM * NN;
        for (int kt = 0; kt < 16; ++kt) {
            int kb = kt * 64;
            for (int i = 0; i < 4; ++i) {
                int idx = i * 256 + tid;
                int r = idx >> 3, c8 = (idx & 7) * 8;
                *reinterpret_cast<s16x8*>(&As[r * 72 + c8]) =
                    *reinterpret_cast<const s16x8*>(Asrc + (int64_t)(m0 + r) * NN + kb + c8);
                *reinterpret_cast<s16x8*>(&Bs[r * 72 + c8]) =
                    *reinterpret_cast<const s16x8*>(Bsrc + (int64_t)(n0 + r) * NN + kb + c8);
            }
            __syncthreads();
            for (int ks = 0; ks < 2; ++ks) {
                s16x8 af[4], bfr[4];
                for (int f = 0; f < 4; ++f)
                    af[f] = *reinterpret_cast<const s16x8*>(&As[(wm + f * 16 + lrow) * 72 + ks * 32 + lgrp * 8]);
                for (int f = 0; f < 4; ++f)
                    bfr[f] = *reinterpret_cast<const s16x8*>(&Bs[(wn + f * 16 + lrow) * 72 + ks * 32 + lgrp * 8]);
                for (int i = 0; i < 4; ++i)
                    for (int j = 0; j < 4; ++j)
                        acc[i][j] = mfma16(af[i], bfr[j], acc[i][j]);
            }
            __syncthreads();
        }
    }
    unsigned short* Cs = sb;   // reuse staging LDS, pitch 136
    auto stageC = [&](int lo) {
        for (int i = 0; i < 4; ++i)
            for (int j = 0; j < 4; ++j)
                for (int r = 0; r < 4; ++r) {
                    float v = acc[i][j][r];
                    unsigned short hv = f2bf(v);
                    if (lo) hv = f2bf(v - bf2f(hv));
                    Cs[(wm + i * 16 + lgrp * 4 + r) * 136 + wn + j * 16 + lrow] = hv;
                }
    };
    auto writeC = [&](unsigned short* dst, int kmode) {
        for (int i = 0; i < 8; ++i) {
            int idx = i * 256 + tid;
            int r = idx >> 4, c8 = (idx & 15) * 8;
            s16x8 v = *reinterpret_cast<const s16x8*>(&Cs[r * 136 + c8]);
            int gm = m0 + r, gn = n0 + c8;
            if (kmode) {
                int hh = gn >> 6, d = gn & 63;
                *reinterpret_cast<s16x8*>(dst + ((int64_t)hh * LL + PP + gm) * DD + d) = v;
            } else {
                *reinterpret_cast<s16x8*>(dst + (int64_t)gm * NN + gn) = v;
            }
        }
    };
    __syncthreads();
    if (z == 0) {
        stageC(0); __syncthreads(); writeC(Qh, 0);
        __syncthreads(); stageC(1); __syncthreads(); writeC(Ql, 0);
    } else if (z == 1) {
        stageC(0); __syncthreads(); writeC(Kall, 1);
    } else {
        stageC(0); __syncthreads(); writeC(Vproj, 0);
    }
}

// ---------------- V transpose: cache_V (f32) + Vproj (bf16) -> VT[h][d][l] bf16
__global__ void k_transV(const float* __restrict__ cV, const unsigned short* __restrict__ Vproj,
                         unsigned short* __restrict__ VT) {
    __shared__ unsigned short Ts[64][72];
    int b = blockIdx.x;
    int hh = b / 80, lt = b % 80;
    int l0 = lt * 64;
    int tid = threadIdx.x;
    if (l0 < PP) {
        for (int i = 0; i < 4; ++i) {
            int idx = i * 256 + tid;
            int r = idx >> 4, c4 = (idx & 15) * 4;
            f32x4 v = *reinterpret_cast<const f32x4*>(cV + ((int64_t)hh * PP + l0 + r) * DD + c4);
            s16x4 o;
            for (int j = 0; j < 4; ++j) o[j] = (short)f2bf(v[j]);
            *reinterpret_cast<s16x4*>(&Ts[r][c4]) = o;
        }
    } else {
        for (int i = 0; i < 2; ++i) {
            int idx = i * 256 + tid;
            int r = idx >> 3, c8 = (idx & 7) * 8;
            *reinterpret_cast<s16x8*>(&Ts[r][c8]) =
                *reinterpret_cast<const s16x8*>(Vproj + (int64_t)(l0 - PP + r) * NN + hh * DD + c8);
        }
    }
    __syncthreads();
    for (int i = 0; i < 2; ++i) {
        int idx = i * 256 + tid;
        int d = idx >> 3, l8 = (idx & 7) * 8;
        s16x8 v;
        for (int j = 0; j < 8; ++j) v[j] = (short)Ts[l8 + j][d];
        *reinterpret_cast<s16x8*>(VT + ((int64_t)hh * DD + d) * LL + l0 + l8) = v;
    }
}

// ---------------- fused attention: pass A (sums) + pass B (normalized emit + PV)
// grid (mt=64, h=16); block 256 = 4 waves; each block: 16 q-rows x full L
__launch_bounds__(256, 4)
__global__ void k_attn2(const unsigned short* __restrict__ Qh, const unsigned short* __restrict__ Ql,
                        const unsigned short* __restrict__ Kall, const unsigned short* __restrict__ VT,
                        const float* __restrict__ noise,
                        float* __restrict__ outO, float* __restrict__ outW, float* __restrict__ outP) {
    __shared__ float sc[16][272];            // scores staging; aliased as ored at the end
    __shared__ unsigned short wls[16][264];  // bf16 normalized weights for PV

    int hh = blockIdx.y, mt = blockIdx.x;
    int m0 = mt * 16;
    int tid = threadIdx.x, lane = tid & 63, wave = tid >> 6;
    int lrow = lane & 15, lgrp = lane >> 4;
    int erow = tid >> 4, cb = tid & 15;      // emit: fixed row per thread

    s16x8 aqh[2], aql[2];
    for (int ks = 0; ks < 2; ++ks) {
        int64_t off = (int64_t)(m0 + lrow) * NN + hh * DD + ks * 32 + lgrp * 8;
        aqh[ks] = *reinterpret_cast<const s16x8*>(Qh + off);
        aql[ks] = *reinterpret_cast<const s16x8*>(Ql + off);
    }
    const unsigned short* Kh = Kall + (int64_t)hh * LL * DD;
    const unsigned short* Vh = VT + (int64_t)hh * DD * LL;
    const float* nzr = noise + ((int64_t)hh * MM + m0 + erow) * LL;
    float* Wr = outW + ((int64_t)hh * MM + m0 + erow) * LL;
    float* Pr = outP + ((int64_t)hh * MM + m0 + erow) * LL;

    // ---- pass A: row sums
    float Sw = 0.f, Sp = 0.f;
    for (int c = 0; c < 20; ++c) {
        int c0 = c * 256;
        {
            f32x4 sacc[4] = {};
            int lb = c0 + wave * 64;
            for (int ks = 0; ks < 2; ++ks)
                for (int lf = 0; lf < 4; ++lf) {
                    s16x8 bk = *reinterpret_cast<const s16x8*>(
                        Kh + (int64_t)(lb + lf * 16 + lrow) * DD + ks * 32 + lgrp * 8);
                    sacc[lf] = mfma16(aqh[ks], bk, sacc[lf]);
                    sacc[lf] = mfma16(aql[ks], bk, sacc[lf]);
                }
            for (int lf = 0; lf < 4; ++lf)
                for (int r = 0; r < 4; ++r)
                    sc[lgrp * 4 + r][wave * 64 + lf * 16 + lrow] = sacc[lf][r];
        }
        __syncthreads();
        for (int q = 0; q < 4; ++q) {
            int col = q * 64 + cb * 4;
            f32x4 s = *reinterpret_cast<const f32x4*>(&sc[erow][col]);
            f32x4 nv = *reinterpret_cast<const f32x4*>(nzr + c0 + col);
            for (int j = 0; j < 4; ++j) {
                Sw += __expf(s[j] - SHC);
                Sp += __expf((s[j] + nv[j]) * (1.f / 1.5f) - SHC);
            }
        }
        __syncthreads();
    }
    for (int d = 1; d < 16; d <<= 1) {
        Sw += __shfl_xor(Sw, d, 64);
        Sp += __shfl_xor(Sp, d, 64);
    }
    float iw = 1.f / Sw, ip = 1.f / Sp;

    // ---- pass B: normalized emit + PV (weights staged for PV are ALREADY normalized,
    // so O needs no further scaling at the end)
    f32x4 oacc[4] = {};
    for (int c = 0; c < 20; ++c) {
        int c0 = c * 256;
        {
            f32x4 sacc[4] = {};
            int lb = c0 + wave * 64;
            for (int ks = 0; ks < 2; ++ks)
                for (int lf = 0; lf < 4; ++lf) {
                    s16x8 bk = *reinterpret_cast<const s16x8*>(
                        Kh + (int64_t)(lb + lf * 16 + lrow) * DD + ks * 32 + lgrp * 8);
                    sacc[lf] = mfma16(aqh[ks], bk, sacc[lf]);
                    sacc[lf] = mfma16(aql[ks], bk, sacc[lf]);
                }
            for (int lf = 0; lf < 4; ++lf)
                for (int r = 0; r < 4; ++r)
                    sc[lgrp * 4 + r][wave * 64 + lf * 16 + lrow] = sacc[lf][r];
        }
        __syncthreads();
        for (int q = 0; q < 4; ++q) {
            int col = q * 64 + cb * 4;
            f32x4 s = *reinterpret_cast<const f32x4*>(&sc[erow][col]);
            f32x4 nv = *reinterpret_cast<const f32x4*>(nzr + c0 + col);
            f32x4 wv, pv;
            for (int j = 0; j < 4; ++j) {
                wv[j] = __expf(s[j] - SHC) * iw;
                pv[j] = __expf((s[j] + nv[j]) * (1.f / 1.5f) - SHC) * ip;
            }
            *reinterpret_cast<f32x4*>(Wr + c0 + col) = wv;
            *reinterpret_cast<f32x4*>(Pr + c0 + col) = pv;
            s16x4 pk;
            for (int j = 0; j < 4; ++j) pk[j] = (short)f2bf(wv[j]);
            *reinterpret_cast<s16x4*>(&wls[erow][col]) = pk;
        }
        __syncthreads();
        for (int ks = 0; ks < 2; ++ks) {
            int k0 = wave * 64 + ks * 32;
            s16x8 bw = *reinterpret_cast<const s16x8*>(&wls[lrow][k0 + lgrp * 8]);
            for (int df = 0; df < 4; ++df) {
                s16x8 av = *reinterpret_cast<const s16x8*>(
                    Vh + (int64_t)(df * 16 + lrow) * LL + c0 + k0 + lgrp * 8);
                oacc[df] = mfma16(av, bw, oacc[df]);
            }
        }
    }
    __syncthreads();
    // ---- cross-wave O^T reduce via LDS (aliases sc), direct O write (already normalized)
    float* ored = &sc[0][0];   // [4][64][17]
    for (int df = 0; df < 4; ++df)
        for (int r = 0; r < 4; ++r)
            ored[(wave * 64 + df * 16 + lgrp * 4 + r) * 17 + lrow] = oacc[df][r];
    __syncthreads();
    for (int i = 0; i < 4; ++i) {
        int idx = i * 256 + tid;
        int m = idx >> 6, d = idx & 63;
        float v = ored[d * 17 + m] + ored[(64 + d) * 17 + m] +
                  ored[(128 + d) * 17 + m] + ored[(192 + d) * 17 + m];
        outO[(int64_t)(m0 + m) * NN + hh * DD + d] = v;
    }
}

extern "C" void kernel_launch(void* const* d_in, const int* in_sizes, int n_in,
                              void* d_out, int out_size, void* d_ws, size_t ws_size,
                              hipStream_t stream) {
    const float* X  = (const float*)d_in[0];
    const float* Wq = (const float*)d_in[1];
    const float* Wk = (const float*)d_in[2];
    const float* Wv = (const float*)d_in[3];
    const float* cK = (const float*)d_in[4];
    const float* cV = (const float*)d_in[5];
    const float* nz = (const float*)d_in[6];

    char* ws = (char*)d_ws;
    const int64_t U = 1 << 21;   // 2 MB units
    unsigned short* Xh    = (unsigned short*)(ws + 0 * U);
    unsigned short* Xl    = (unsigned short*)(ws + 1 * U);
    unsigned short* WhT   = (unsigned short*)(ws + 2 * U);   // 3 units
    unsigned short* WlT   = (unsigned short*)(ws + 5 * U);   // 3 units
    unsigned short* Qh    = (unsigned short*)(ws + 8 * U);
    unsigned short* Ql    = (unsigned short*)(ws + 9 * U);
    unsigned short* Kall  = (unsigned short*)(ws + 10 * U);  // 5 units
    unsigned short* Vproj = (unsigned short*)(ws + 15 * U);
    unsigned short* VT    = (unsigned short*)(ws + 16 * U);  // 5 units

    float* outO = (float*)d_out;
    float* outW = outO + (int64_t)MM * NN;
    float* outP = outW + (int64_t)HH * MM * LL;

    k_prep<<<2048, 256, 0, stream>>>(X, cK, Xh, Xl, Kall);
    k_transW<<<dim3(16, 16, 3), 256, 0, stream>>>(Wq, Wk, Wv, WhT, WlT);
    k_gemm<<<dim3(8, 8, 3), 256, 0, stream>>>(Xh, Xl, WhT, WlT, Qh, Ql, Kall, Vproj);
    k_transV<<<1280, 256, 0, stream>>>(cV, Vproj, VT);
    k_attn2<<<dim3(64, 16), 256, 0, stream>>>(Qh, Ql, Kall, VT, nz, outO, outW, outP);
}